// Round 2
// baseline (2733.330 us; speedup 1.0000x reference)
//
#include <hip/hip_runtime.h>
#include <stdint.h>

#define N_USERS 100000
#define N_ITEMS 50000
#define NTOT    150000
#define D       64
#define NNZ     8000000
#define IT      4
#define SCAN_BLK 256
#define CHUNK   (SCAN_BLK*IT)                 /* 1024 */
#define NB      ((NTOT + CHUNK - 1)/CHUNK)    /* 147  */

// ---------------- hop-0 init + zero counters ----------------
__global__ void init_hop0(const float* __restrict__ ue, const float* __restrict__ ie,
                          float* __restrict__ out, int* __restrict__ cnt) {
    int tid = blockIdx.x * blockDim.x + threadIdx.x;
    if (tid < NTOT * (D/4)) {               // one float4 per thread
        int r = tid >> 4;                   // D/4 == 16 float4 per row
        int q = tid & 15;
        const float4* src = (r < N_USERS)
            ? (const float4*)(ue + (size_t)r * D)
            : (const float4*)(ie + (size_t)(r - N_USERS) * D);
        float4 v = src[q];
        ((float4*)(out + (size_t)r * 4 * D))[q] = v;   // slot 0 of [N,4,64]
    }
    if (tid < NTOT) cnt[tid] = 0;
}

// ---------------- row histogram ----------------
__global__ void hist_rows(const int* __restrict__ rows, int* __restrict__ cnt) {
    int e = blockIdx.x * blockDim.x + threadIdx.x;
    if (e < NNZ) atomicAdd(&cnt[__builtin_nontemporal_load(&rows[e])], 1);
}

// ---------------- 3-phase exclusive scan ----------------
__global__ void scan_p1(const int* __restrict__ cnt, int* __restrict__ partials) {
    __shared__ int sm[SCAN_BLK];
    int t = threadIdx.x, b = blockIdx.x;
    int base = b * CHUNK + t * IT;
    int s = 0;
#pragma unroll
    for (int j = 0; j < IT; ++j) { int i = base + j; s += (i < NTOT) ? cnt[i] : 0; }
    sm[t] = s; __syncthreads();
    for (int off = 1; off < SCAN_BLK; off <<= 1) {
        int x = (t >= off) ? sm[t - off] : 0;
        __syncthreads();
        sm[t] += x;
        __syncthreads();
    }
    if (t == SCAN_BLK - 1) partials[b] = sm[t];
}

__global__ void scan_p2(int* __restrict__ partials) {
    __shared__ int sm[SCAN_BLK];
    int t = threadIdx.x;
    int v = (t < NB) ? partials[t] : 0;
    sm[t] = v; __syncthreads();
    for (int off = 1; off < SCAN_BLK; off <<= 1) {
        int x = (t >= off) ? sm[t - off] : 0;
        __syncthreads();
        sm[t] += x;
        __syncthreads();
    }
    if (t < NB) partials[t] = sm[t] - v;      // exclusive
}

__global__ void scan_p3(const int* __restrict__ partials, int* __restrict__ cnt /* -> cursor */,
                        int* __restrict__ row_ptr) {
    __shared__ int sm[SCAN_BLK];
    int t = threadIdx.x, b = blockIdx.x;
    int base = b * CHUNK + t * IT;
    int c[IT]; int s = 0;
#pragma unroll
    for (int j = 0; j < IT; ++j) { int i = base + j; c[j] = (i < NTOT) ? cnt[i] : 0; s += c[j]; }
    sm[t] = s; __syncthreads();
    for (int off = 1; off < SCAN_BLK; off <<= 1) {
        int x = (t >= off) ? sm[t - off] : 0;
        __syncthreads();
        sm[t] += x;
        __syncthreads();
    }
    int off = partials[b] + sm[t] - s;        // exclusive offset for this thread
#pragma unroll
    for (int j = 0; j < IT; ++j) {
        int i = base + j;
        if (i < NTOT) { row_ptr[i] = off; cnt[i] = off; off += c[j]; }
    }
    if (b == 0 && t == 0) row_ptr[NTOT] = NNZ;
}

// ---------------- scatter edges into CSR order, pack col+keepmask+val ----------------
__global__ void scatter_edges(const int* __restrict__ rows, const int* __restrict__ cols,
                              const float* __restrict__ vals, const float* __restrict__ erand,
                              int* __restrict__ cursor, uint2* __restrict__ edges) {
    int e = blockIdx.x * blockDim.x + threadIdx.x;
    if (e >= NNZ) return;
    int r = __builtin_nontemporal_load(&rows[e]);
    unsigned m = 0;
#pragma unroll
    for (int h = 0; h < 3; ++h) {
        float u = __builtin_nontemporal_load(&erand[(size_t)h * NNZ + e]);
        if (floorf(0.5f + u) != 0.0f) m |= (1u << h);   // exact torch-style keep
    }
    unsigned cm = (unsigned)__builtin_nontemporal_load(&cols[e]) | (m << 18); // col < 2^18
    float v = __builtin_nontemporal_load(&vals[e]);
    int pos = atomicAdd(&cursor[r], 1);
    edges[pos] = make_uint2(cm, __float_as_uint(v));
}

// ---------------- gather SpMM per hop: one wave per row, 16-deep MLP ----------------
#define CH 16
__global__ __launch_bounds__(256) void spmm_hop(const int* __restrict__ row_ptr,
                                                const uint2* __restrict__ edges,
                                                const float* __restrict__ mrand,
                                                float* __restrict__ out, int h) {
    int w    = (blockIdx.x * blockDim.x + threadIdx.x) >> 6;
    int lane = threadIdx.x & 63;
    if (w >= NTOT) return;
    int r = w;
    int start = row_ptr[r], end = row_ptr[r + 1];
    const float* prev = out + (size_t)h * D;   // slot h; index (size_t)c*256 + lane
    float acc = 0.f;
    unsigned hb = 1u << (18 + h);
    for (int e = start; e < end; e += CH) {
        float ww[CH], vv[CH];
#pragma unroll
        for (int j = 0; j < CH; ++j) {
            int idx = e + j;
            int cl  = idx < end ? idx : start;     // safe: loop entered => start < end
            uint2 ed = edges[cl];
            bool keep = (idx < end) && (ed.x & hb);
            // dropped/OOB edges gather row 0 (L1-hot) with weight 0 -> unconditional load,
            // compiler can issue all CH gathers before any fma (MLP depth 16)
            int c = keep ? (int)(ed.x & 0x3FFFFu) : 0;
            ww[j] = keep ? __uint_as_float(ed.y) * 2.0f : 0.0f;
            vv[j] = prev[(size_t)c * 256 + lane];
        }
#pragma unroll
        for (int j = 0; j < CH; ++j) acc = fmaf(ww[j], vv[j], acc);
    }
    float u = __builtin_nontemporal_load(&mrand[((size_t)h * NTOT + r) * D + lane]);
    float res = (u >= 0.1f) ? acc * (1.0f / 0.9f) : 0.0f;
    out[((size_t)r * 4 + (h + 1)) * D + lane] = res;
}

extern "C" void kernel_launch(void* const* d_in, const int* in_sizes, int n_in,
                              void* d_out, int out_size, void* d_ws, size_t ws_size,
                              hipStream_t stream) {
    const float* ue    = (const float*)d_in[0];
    const float* ie    = (const float*)d_in[1];
    const int*   rows  = (const int*)  d_in[2];
    const int*   cols  = (const int*)  d_in[3];
    const float* vals  = (const float*)d_in[4];
    const float* erand = (const float*)d_in[5];
    const float* mrand = (const float*)d_in[6];
    float* out = (float*)d_out;

    // workspace layout (≈65.3 MB)
    char* ws = (char*)d_ws;
    size_t off = 0;
    int* cnt      = (int*)(ws + off); off += (size_t)NTOT * 4;        off = (off + 255) & ~(size_t)255;
    int* row_ptr  = (int*)(ws + off); off += (size_t)(NTOT + 1) * 4;  off = (off + 255) & ~(size_t)255;
    int* partials = (int*)(ws + off); off += (size_t)NB * 4;          off = (off + 255) & ~(size_t)255;
    uint2* edges  = (uint2*)(ws + off); off += (size_t)NNZ * 8;

    init_hop0<<<(NTOT * 16 + 255) / 256, 256, 0, stream>>>(ue, ie, out, cnt);
    hist_rows<<<(NNZ + 255) / 256, 256, 0, stream>>>(rows, cnt);
    scan_p1<<<NB, SCAN_BLK, 0, stream>>>(cnt, partials);
    scan_p2<<<1, SCAN_BLK, 0, stream>>>(partials);
    scan_p3<<<NB, SCAN_BLK, 0, stream>>>(partials, cnt, row_ptr);
    scatter_edges<<<(NNZ + 255) / 256, 256, 0, stream>>>(rows, cols, vals, erand, cnt, edges);
    for (int h = 0; h < 3; ++h) {
        spmm_hop<<<(NTOT * 64 + 255) / 256, 256, 0, stream>>>(row_ptr, edges, mrand, out, h);
    }
}

// Round 3
// 1822.407 us; speedup vs baseline: 1.4998x; 1.4998x over previous
//
#include <hip/hip_runtime.h>
#include <stdint.h>

#define N_USERS 100000
#define N_ITEMS 50000
#define NTOT    150000
#define D       64
#define NNZ     8000000
#define IT      4
#define SCAN_BLK 256
#define CHUNK   (SCAN_BLK*IT)                 /* 1024 */
#define NB      ((NTOT + CHUNK - 1)/CHUNK)    /* 147  */
#define CH      16

typedef unsigned short ushort_t;

__device__ __forceinline__ ushort_t f2bf(float f) {          // RNE f32->bf16
    unsigned u = __float_as_uint(f);
    unsigned r = (u + 0x7FFFu + ((u >> 16) & 1u)) >> 16;
    return (ushort_t)r;
}
__device__ __forceinline__ float bf2f(ushort_t t) {
    return __uint_as_float(((unsigned)t) << 16);
}

// ---------------- hop-0 init + zero counters (+ optional bf16 table 0) ----------------
__global__ void init_hop0(const float* __restrict__ ue, const float* __restrict__ ie,
                          float* __restrict__ out, int* __restrict__ cnt,
                          ushort_t* __restrict__ tb0) {
    int tid = blockIdx.x * blockDim.x + threadIdx.x;
    if (tid < NTOT * (D/4)) {               // one float4 per thread
        int r = tid >> 4;                   // D/4 == 16 float4 per row
        int q = tid & 15;
        const float4* src = (r < N_USERS)
            ? (const float4*)(ue + (size_t)r * D)
            : (const float4*)(ie + (size_t)(r - N_USERS) * D);
        float4 v = src[q];
        ((float4*)(out + (size_t)r * 4 * D))[q] = v;   // slot 0 of [N,4,64]
        if (tb0) {
            ushort4 b; b.x = f2bf(v.x); b.y = f2bf(v.y); b.z = f2bf(v.z); b.w = f2bf(v.w);
            ((ushort4*)(tb0 + (size_t)r * D))[q] = b;
        }
    }
    if (tid < NTOT) cnt[tid] = 0;
}

// ---------------- row histogram ----------------
__global__ void hist_rows(const int* __restrict__ rows, int* __restrict__ cnt) {
    int e = blockIdx.x * blockDim.x + threadIdx.x;
    if (e < NNZ) atomicAdd(&cnt[rows[e]], 1);
}

// ---------------- 3-phase exclusive scan ----------------
__global__ void scan_p1(const int* __restrict__ cnt, int* __restrict__ partials) {
    __shared__ int sm[SCAN_BLK];
    int t = threadIdx.x, b = blockIdx.x;
    int base = b * CHUNK + t * IT;
    int s = 0;
#pragma unroll
    for (int j = 0; j < IT; ++j) { int i = base + j; s += (i < NTOT) ? cnt[i] : 0; }
    sm[t] = s; __syncthreads();
    for (int off = 1; off < SCAN_BLK; off <<= 1) {
        int x = (t >= off) ? sm[t - off] : 0;
        __syncthreads();
        sm[t] += x;
        __syncthreads();
    }
    if (t == SCAN_BLK - 1) partials[b] = sm[t];
}

__global__ void scan_p2(int* __restrict__ partials) {
    __shared__ int sm[SCAN_BLK];
    int t = threadIdx.x;
    int v = (t < NB) ? partials[t] : 0;
    sm[t] = v; __syncthreads();
    for (int off = 1; off < SCAN_BLK; off <<= 1) {
        int x = (t >= off) ? sm[t - off] : 0;
        __syncthreads();
        sm[t] += x;
        __syncthreads();
    }
    if (t < NB) partials[t] = sm[t] - v;      // exclusive
}

__global__ void scan_p3(const int* __restrict__ partials, int* __restrict__ cnt /* -> cursor */,
                        int* __restrict__ row_ptr) {
    __shared__ int sm[SCAN_BLK];
    int t = threadIdx.x, b = blockIdx.x;
    int base = b * CHUNK + t * IT;
    int c[IT]; int s = 0;
#pragma unroll
    for (int j = 0; j < IT; ++j) { int i = base + j; c[j] = (i < NTOT) ? cnt[i] : 0; s += c[j]; }
    sm[t] = s; __syncthreads();
    for (int off = 1; off < SCAN_BLK; off <<= 1) {
        int x = (t >= off) ? sm[t - off] : 0;
        __syncthreads();
        sm[t] += x;
        __syncthreads();
    }
    int off = partials[b] + sm[t] - s;        // exclusive offset for this thread
#pragma unroll
    for (int j = 0; j < IT; ++j) {
        int i = base + j;
        if (i < NTOT) { row_ptr[i] = off; cnt[i] = off; off += c[j]; }
    }
    if (b == 0 && t == 0) row_ptr[NTOT] = NNZ;
}

// ---------------- scatter edges into CSR order, pack col+keepmask+val ----------------
__global__ void scatter_edges(const int* __restrict__ rows, const int* __restrict__ cols,
                              const float* __restrict__ vals, const float* __restrict__ erand,
                              int* __restrict__ cursor, uint2* __restrict__ edges) {
    int e = blockIdx.x * blockDim.x + threadIdx.x;
    if (e >= NNZ) return;
    int r = rows[e];
    unsigned m = 0;
#pragma unroll
    for (int h = 0; h < 3; ++h) {
        float u = erand[(size_t)h * NNZ + e];
        if (floorf(0.5f + u) != 0.0f) m |= (1u << h);   // exact torch-style keep
    }
    unsigned cm = (unsigned)cols[e] | (m << 18);        // col < 2^18
    float v = vals[e];
    int pos = atomicAdd(&cursor[r], 1);
    edges[pos] = make_uint2(cm, __float_as_uint(v));
}

// ---------------- gather SpMM per hop: one wave per row ----------------
// Scalarized edge records (wave-uniform) -> keep test is a scalar branch;
// kept edges issue gathers back-to-back within a CH-chunk (MLP), dropped
// edges cost a few SALU ops and no memory traffic.
template<bool BF>
__global__ __launch_bounds__(256) void spmm_hop(const int* __restrict__ row_ptr,
                                                const uint2* __restrict__ edges,
                                                const float* __restrict__ mrand,
                                                float* __restrict__ out,
                                                const ushort_t* __restrict__ tb_in,
                                                ushort_t* __restrict__ tb_out, int h) {
    int w    = (blockIdx.x * blockDim.x + threadIdx.x) >> 6;
    int lane = threadIdx.x & 63;
    if (w >= NTOT) return;
    int r = w;
    int start = __builtin_amdgcn_readfirstlane(row_ptr[r]);
    int end   = __builtin_amdgcn_readfirstlane(row_ptr[r + 1]);
    const float* prevf = out + (size_t)h * D;     // f32 fallback: index c*256 + lane
    float acc = 0.f;
    unsigned hb = 1u << (18 + h);

    int e = start;
    for (; e + CH <= end; e += CH) {
        float ww[CH], vv[CH];
#pragma unroll
        for (int j = 0; j < CH; ++j) {
            uint2 ed = edges[e + j];
            unsigned x = __builtin_amdgcn_readfirstlane(ed.x);
            unsigned y = __builtin_amdgcn_readfirstlane(ed.y);
            if (x & hb) {                          // scalar branch: skip dropped
                int c = (int)(x & 0x3FFFFu);
                vv[j] = BF ? bf2f(tb_in[(size_t)c * D + lane])
                           : prevf[(size_t)c * 256 + lane];
                ww[j] = __uint_as_float(y) * 2.0f;
            } else { vv[j] = 0.f; ww[j] = 0.f; }
        }
#pragma unroll
        for (int j = 0; j < CH; ++j) acc = fmaf(ww[j], vv[j], acc);
    }
    for (; e < end; ++e) {                         // tail
        uint2 ed = edges[e];
        unsigned x = __builtin_amdgcn_readfirstlane(ed.x);
        unsigned y = __builtin_amdgcn_readfirstlane(ed.y);
        if (x & hb) {
            int c = (int)(x & 0x3FFFFu);
            float v = BF ? bf2f(tb_in[(size_t)c * D + lane])
                         : prevf[(size_t)c * 256 + lane];
            acc = fmaf(__uint_as_float(y) * 2.0f, v, acc);
        }
    }

    float u = __builtin_nontemporal_load(&mrand[((size_t)h * NTOT + r) * D + lane]);
    float res = (u >= 0.1f) ? acc * (1.0f / 0.9f) : 0.0f;
    out[((size_t)r * 4 + (h + 1)) * D + lane] = res;
    if (BF) tb_out[(size_t)r * D + lane] = f2bf(res);
}

extern "C" void kernel_launch(void* const* d_in, const int* in_sizes, int n_in,
                              void* d_out, int out_size, void* d_ws, size_t ws_size,
                              hipStream_t stream) {
    const float* ue    = (const float*)d_in[0];
    const float* ie    = (const float*)d_in[1];
    const int*   rows  = (const int*)  d_in[2];
    const int*   cols  = (const int*)  d_in[3];
    const float* vals  = (const float*)d_in[4];
    const float* erand = (const float*)d_in[5];
    const float* mrand = (const float*)d_in[6];
    float* out = (float*)d_out;

    // workspace layout
    char* ws = (char*)d_ws;
    size_t off = 0;
    int* cnt      = (int*)(ws + off); off += (size_t)NTOT * 4;        off = (off + 255) & ~(size_t)255;
    int* row_ptr  = (int*)(ws + off); off += (size_t)(NTOT + 1) * 4;  off = (off + 255) & ~(size_t)255;
    int* partials = (int*)(ws + off); off += (size_t)NB * 4;          off = (off + 255) & ~(size_t)255;
    uint2* edges  = (uint2*)(ws + off); off += (size_t)NNZ * 8;       off = (off + 255) & ~(size_t)255;
    // optional bf16 ping-pong tables (19.2 MB each)
    size_t tb_bytes = (size_t)NTOT * D * sizeof(ushort_t);
    bool use_bf = (off + 2 * tb_bytes) <= ws_size;
    ushort_t* tbA = use_bf ? (ushort_t*)(ws + off) : nullptr;
    ushort_t* tbB = use_bf ? (ushort_t*)(ws + off + tb_bytes) : nullptr;

    init_hop0<<<(NTOT * 16 + 255) / 256, 256, 0, stream>>>(ue, ie, out, cnt, tbA);
    hist_rows<<<(NNZ + 255) / 256, 256, 0, stream>>>(rows, cnt);
    scan_p1<<<NB, SCAN_BLK, 0, stream>>>(cnt, partials);
    scan_p2<<<1, SCAN_BLK, 0, stream>>>(partials);
    scan_p3<<<NB, SCAN_BLK, 0, stream>>>(partials, cnt, row_ptr);
    scatter_edges<<<(NNZ + 255) / 256, 256, 0, stream>>>(rows, cols, vals, erand, cnt, edges);
    int grid = (NTOT * 64 + 255) / 256;
    if (use_bf) {
        for (int h = 0; h < 3; ++h) {
            ushort_t* ti = (h & 1) ? tbB : tbA;
            ushort_t* to = (h & 1) ? tbA : tbB;
            spmm_hop<true><<<grid, 256, 0, stream>>>(row_ptr, edges, mrand, out, ti, to, h);
        }
    } else {
        for (int h = 0; h < 3; ++h) {
            spmm_hop<false><<<grid, 256, 0, stream>>>(row_ptr, edges, mrand, out, nullptr, nullptr, h);
        }
    }
}